// Round 5
// baseline (65.992 us; speedup 1.0000x reference)
//
#include <hip/hip_runtime.h>
#include <hip/hip_bf16.h>

#define B_TOTAL 1000000
#define NBLK ((B_TOTAL + 255) / 256)

// upper-tri packed index for (i,j), i<=j, of a 6x6: row i starts at 6i - i(i-1)/2
__device__ __forceinline__ constexpr int up_idx(int i, int j) {
    return i * 6 - i * (i - 1) / 2 + (j - i);
}

// Cholesky (lower) of symmetric 6x6 given packed upper-tri v[21], diag += 1e-5.
// S[i][j] (i>=j) = v[up_idx(j,i)]. Outputs lower L and reciprocal diagonal.
__device__ __forceinline__ void chol6(const float* v, float L[6][6], float dinv[6]) {
#pragma unroll
    for (int j = 0; j < 6; ++j) {
        float s = v[up_idx(j, j)] + 1e-5f;
#pragma unroll
        for (int k = 0; k < 6; ++k)
            if (k < j) s -= L[j][k] * L[j][k];
        float d = sqrtf(s);
        L[j][j] = d;
        float inv = 1.0f / d;
        dinv[j] = inv;
#pragma unroll
        for (int i = 0; i < 6; ++i)
            if (i > j) {
                float a = v[up_idx(j, i)];
#pragma unroll
                for (int k = 0; k < 6; ++k)
                    if (k < j) a -= L[i][k] * L[j][k];
                L[i][j] = a * inv;
            }
    }
}

__global__ void __launch_bounds__(256) kl_huber_kernel(const float* __restrict__ target,
                                                       const float* __restrict__ pred,
                                                       double* __restrict__ acc) {
    int b = blockIdx.x * blockDim.x + threadIdx.x;
    float contrib = 0.0f;
    if (b < B_TOTAL) {
        const float* tb = target + (long)b * 21;
        const float* pb = pred + (long)b * 21;
        float t[21], p[21];
#pragma unroll
        for (int k = 0; k < 21; ++k) t[k] = tb[k];
#pragma unroll
        for (int k = 0; k < 21; ++k) p[k] = pb[k];

        // Huber, delta = 1
        float hs = 0.0f;
#pragma unroll
        for (int k = 0; k < 21; ++k) {
            float d = p[k] - t[k];
            float ad = fabsf(d);
            hs += (ad < 1.0f) ? 0.5f * d * d : ad - 0.5f;
        }

        float Lt[6][6], Lp[6][6], dti[6], dpi[6];
        chol6(t, Lt, dti);
        chol6(p, Lp, dpi);

        // M = Lt^{-1} Lp (forward substitution per column), tr = sum(M*M)
        float tr = 0.0f;
#pragma unroll
        for (int c = 0; c < 6; ++c) {
            float m[6];
#pragma unroll
            for (int r = 0; r < 6; ++r)
                if (r >= c) {
                    float s = Lp[r][c];
#pragma unroll
                    for (int k = 0; k < 6; ++k)
                        if (k >= c && k < r) s -= Lt[r][k] * m[k];
                    m[r] = s * dti[r];
                    tr += m[r] * m[r];
                }
        }

        // logdet_t - logdet_p = 2 * log(prod(Lt_ii) / prod(Lp_ii))
        float ratio = 1.0f;
#pragma unroll
        for (int i = 0; i < 6; ++i) ratio *= Lt[i][i] * dpi[i];
        float kl = 0.5f * (tr - 6.0f) + logf(ratio);

        contrib = kl + hs * (1.0f / 21.0f);
    }

    // wave (64-lane) reduce
#pragma unroll
    for (int off = 32; off > 0; off >>= 1) contrib += __shfl_down(contrib, off);

    __shared__ float wsum[4];
    int lane = threadIdx.x & 63;
    int wid = threadIdx.x >> 6;
    if (lane == 0) wsum[wid] = contrib;
    __syncthreads();
    if (threadIdx.x == 0) {
        float bs = wsum[0] + wsum[1] + wsum[2] + wsum[3];
        atomicAdd(acc, (double)bs);
    }
}

__global__ void finalize_kernel(const double* __restrict__ acc, float* __restrict__ out) {
    if (threadIdx.x == 0 && blockIdx.x == 0) {
        out[0] = (float)(acc[0] / (double)B_TOTAL);
    }
}

extern "C" void kernel_launch(void* const* d_in, const int* in_sizes, int n_in,
                              void* d_out, int out_size, void* d_ws, size_t ws_size,
                              hipStream_t stream) {
    const float* target = (const float*)d_in[0];
    const float* pred = (const float*)d_in[1];
    double* acc = (double*)d_ws;

    hipMemsetAsync(d_ws, 0, sizeof(double), stream);
    kl_huber_kernel<<<NBLK, 256, 0, stream>>>(target, pred, acc);
    finalize_kernel<<<1, 64, 0, stream>>>(acc, (float*)d_out);
}